// Round 2
// baseline (448.962 us; speedup 1.0000x reference)
//
#include <hip/hip_runtime.h>

constexpr int B      = 4;
constexpr int T      = 4096;
constexpr int C      = 64;                 // input dim
constexpr int H      = 64;                 // head dim
constexpr int TILE   = 32;                 // query rows per block
constexpr int HALO   = 2;                  // window radius
constexpr int HR     = TILE + 2 * HALO;    // 36 halo rows
constexpr int LS     = 68;                 // LDS row stride (floats): keeps float4 alignment, rotates banks by 4/row
constexpr int NT     = 256;
constexpr int NTILES = T / TILE;           // 128

__global__ __launch_bounds__(NT, 2)
void sparse_attn_fused(const float* __restrict__ x,
                       const float* __restrict__ Wq,
                       const float* __restrict__ Wk,
                       const float* __restrict__ Wv,
                       float* __restrict__ out)
{
    __shared__ float sX[HR][LS];      // x halo rows
    __shared__ float sQ[TILE][LS];
    __shared__ float sK[HR][LS];
    __shared__ float sV[HR][LS];
    __shared__ float sS[TILE][8];     // scores, then probs (5 used per row)
    __shared__ float sBV[TILE][8];    // per-row 8-float 16B-aligned band window
    __shared__ int   sBG[TILE];       // per-row first float4-group index of the window

    const int tid  = threadIdx.x;
    const int b    = blockIdx.x / NTILES;
    const int tile = blockIdx.x % NTILES;
    const int row0 = tile * TILE;
    const float* xb = x + (size_t)b * T * C;

    // ---- stage x halo rows into LDS (zero-padded at batch edges) ----
    for (int s = tid; s < HR * (C / 4); s += NT) {
        const int lr = s >> 4;
        const int c4 = (s & 15) << 2;
        const int gr = row0 + lr - HALO;
        float4 v = make_float4(0.f, 0.f, 0.f, 0.f);
        if (gr >= 0 && gr < T) v = *(const float4*)(xb + (size_t)gr * C + c4);
        *(float4*)&sX[lr][c4] = v;
    }

    const int h = tid & 63;      // head-dim column this lane owns
    const int w = tid >> 6;      // wave id 0..3

    // W row for this lane lives in registers (16 KB per matrix, L2-resident across 512 blocks)
    float4 wr[16];
#pragma unroll
    for (int c4 = 0; c4 < 16; ++c4) wr[c4] = *(const float4*)(Wq + h * C + c4 * 4);

    __syncthreads();

    // ---- Q = X[tile] @ Wq^T : wave w computes rows w*8..w*8+7; sX row broadcast, free ----
#pragma unroll
    for (int ii = 0; ii < 8; ++ii) {
        const int i = w * 8 + ii;
        float acc = 0.f;
#pragma unroll
        for (int c4 = 0; c4 < 16; ++c4) {
            const float4 xv = *(const float4*)&sX[i + HALO][c4 * 4];
            acc = fmaf(xv.x, wr[c4].x, acc);
            acc = fmaf(xv.y, wr[c4].y, acc);
            acc = fmaf(xv.z, wr[c4].z, acc);
            acc = fmaf(xv.w, wr[c4].w, acc);
        }
        sQ[i][h] = acc;
    }

    // ---- K = X[halo] @ Wk^T : wave w computes rows w*9..w*9+8 ----
#pragma unroll
    for (int c4 = 0; c4 < 16; ++c4) wr[c4] = *(const float4*)(Wk + h * C + c4 * 4);
#pragma unroll
    for (int ii = 0; ii < 9; ++ii) {
        const int l = w * 9 + ii;
        float acc = 0.f;
#pragma unroll
        for (int c4 = 0; c4 < 16; ++c4) {
            const float4 xv = *(const float4*)&sX[l][c4 * 4];
            acc = fmaf(xv.x, wr[c4].x, acc);
            acc = fmaf(xv.y, wr[c4].y, acc);
            acc = fmaf(xv.z, wr[c4].z, acc);
            acc = fmaf(xv.w, wr[c4].w, acc);
        }
        sK[l][h] = acc;
    }

    // ---- V = X[halo] @ Wv^T ----
#pragma unroll
    for (int c4 = 0; c4 < 16; ++c4) wr[c4] = *(const float4*)(Wv + h * C + c4 * 4);
#pragma unroll
    for (int ii = 0; ii < 9; ++ii) {
        const int l = w * 9 + ii;
        float acc = 0.f;
#pragma unroll
        for (int c4 = 0; c4 < 16; ++c4) {
            const float4 xv = *(const float4*)&sX[l][c4 * 4];
            acc = fmaf(xv.x, wr[c4].x, acc);
            acc = fmaf(xv.y, wr[c4].y, acc);
            acc = fmaf(xv.z, wr[c4].z, acc);
            acc = fmaf(xv.w, wr[c4].w, acc);
        }
        sV[l][h] = acc;
    }

    __syncthreads();

    // ---- scores: 32 rows x 5 offsets on 160 threads ----
    if (tid < TILE * 5) {
        const int i  = tid / 5;
        const int dj = tid % 5;
        const int jg = row0 + i - HALO + dj;
        float sc = -__builtin_inff();
        if (jg >= 0 && jg < T) {
            float acc = 0.f;
#pragma unroll
            for (int c4 = 0; c4 < C; c4 += 4) {
                const float4 q = *(const float4*)&sQ[i][c4];
                const float4 k = *(const float4*)&sK[i + dj][c4];
                acc = fmaf(q.x, k.x, acc);
                acc = fmaf(q.y, k.y, acc);
                acc = fmaf(q.z, k.z, acc);
                acc = fmaf(q.w, k.w, acc);
            }
            // scale = C^-0.5 = 0.125 ; +1 bias inside band for j > i (dj > 2), per triu(ones,1)
            sc = acc * 0.125f + (dj > 2 ? 1.0f : 0.0f);
        }
        sS[i][dj] = sc;
    }
    __syncthreads();

    // ---- softmax per row; build aligned 8-float band window + group index ----
    if (tid < TILE) {
        const int i  = tid;
        const int ig = row0 + i;
        float sc[5];
        float m = -__builtin_inff();
#pragma unroll
        for (int d = 0; d < 5; ++d) { sc[d] = sS[i][d]; m = fmaxf(m, sc[d]); }
        float p[5];
        float sum = 0.f;
#pragma unroll
        for (int d = 0; d < 5; ++d) { p[d] = expf(sc[d] - m); sum += p[d]; }
        const float inv = 1.f / sum;

        const int j0   = ig - HALO;
        const int G0   = (j0 > 0 ? j0 : 0) >> 2;     // first touched float4 group
        const int base = G0 << 2;
        float bw[8];
#pragma unroll
        for (int q = 0; q < 8; ++q) bw[q] = 0.f;
#pragma unroll
        for (int d = 0; d < 5; ++d) {
            const float pv = p[d] * inv;             // exp(-inf)=0 -> prob 0 for invalid j
            sS[i][d] = pv;
            const int off = j0 + d - base;
            if (off >= 0 && off < 8) bw[off] = pv;   // j>=T entries are 0, harmless
        }
        sBG[i] = G0;
#pragma unroll
        for (int q = 0; q < 8; ++q) sBV[i][q] = bw[q];
    }
    __syncthreads();

    // ================= no barriers below this line: stores free to drain =================

    // ---- op = P @ V : 512 float4 outputs, coalesced ----
    for (int s = tid; s < TILE * (H / 4); s += NT) {
        const int r  = s >> 4;
        const int hq = (s & 15) << 2;
        float4 acc = make_float4(0.f, 0.f, 0.f, 0.f);
#pragma unroll
        for (int d = 0; d < 5; ++d) {
            const float pv = sS[r][d];
            const float4 vv = *(const float4*)&sV[r + d][hq];
            acc.x = fmaf(pv, vv.x, acc.x);
            acc.y = fmaf(pv, vv.y, acc.y);
            acc.z = fmaf(pv, vv.z, acc.z);
            acc.w = fmaf(pv, vv.w, acc.w);
        }
        *(float4*)(out + ((size_t)b * T + row0 + r) * H + hq) = acc;
    }

    // ---- attn rows: single pass, each float4 written exactly once (zero or band window) ----
    const size_t attnBase = (size_t)B * T * H;
    float4* dst = (float4*)(out + attnBase + ((size_t)b * T + row0) * T);
    const float4 z = make_float4(0.f, 0.f, 0.f, 0.f);
    for (int rr = 0; rr < TILE; ++rr) {
        const int   G0 = sBG[rr];                       // uniform -> LDS broadcast
        const float4 V0 = *(const float4*)&sBV[rr][0];
        const float4 V1 = *(const float4*)&sBV[rr][4];
        float4* drow = dst + rr * (T / 4);
#pragma unroll
        for (int kk = 0; kk < 4; ++kk) {
            const int g = kk * NT + tid;               // 1 KB per wave per store, coalesced
            float4 v = z;
            if (g == G0)          v = V0;
            else if (g == G0 + 1) v = V1;              // G0+1 may be 1024 at the top edge: never matches, fine
            drow[g] = v;
        }
    }
}

extern "C" void kernel_launch(void* const* d_in, const int* in_sizes, int n_in,
                              void* d_out, int out_size, void* d_ws, size_t ws_size,
                              hipStream_t stream) {
    (void)in_sizes; (void)n_in; (void)d_ws; (void)ws_size; (void)out_size;
    const float* x  = (const float*)d_in[0];
    const float* Wq = (const float*)d_in[1];
    const float* Wk = (const float*)d_in[2];
    const float* Wv = (const float*)d_in[3];
    float* out = (float*)d_out;
    sparse_attn_fused<<<dim3(B * NTILES), dim3(NT), 0, stream>>>(x, Wq, Wk, Wv, out);
}

// Round 3
// 434.453 us; speedup vs baseline: 1.0334x; 1.0334x over previous
//
#include <hip/hip_runtime.h>

constexpr int B      = 4;
constexpr int T      = 4096;
constexpr int C      = 64;                 // input dim
constexpr int H      = 64;                 // head dim
constexpr int TILE   = 32;                 // query rows per block
constexpr int HALO   = 2;                  // window radius
constexpr int HR     = TILE + 2 * HALO;    // 36 halo rows
constexpr int LS     = 68;                 // LDS row stride (floats): float4-aligned, rotates banks by 4/row
constexpr int NT     = 256;
constexpr int NTILES = T / TILE;           // 128

typedef float f32x4 __attribute__((ext_vector_type(4)));

__device__ __forceinline__ void store_nt(f32x4* p, f32x4 v) {
    __builtin_nontemporal_store(v, p);     // global_store_dwordx4 ... nt : no write-allocate RMW
}

__global__ __launch_bounds__(NT, 2)
void sparse_attn_fused(const float* __restrict__ x,
                       const float* __restrict__ Wq,
                       const float* __restrict__ Wk,
                       const float* __restrict__ Wv,
                       float* __restrict__ out)
{
    __shared__ float sX[HR][LS];       // x halo rows
    __shared__ float sQ[TILE][LS];
    __shared__ float sK[HR][LS];
    __shared__ float sV[HR][LS];
    __shared__ float sS[TILE][8];      // scores, then probs (5 used per row)
    __shared__ f32x4 sBV[TILE][2];     // per-row 8-float 16B-aligned band window
    __shared__ int   sBG[TILE];        // per-row first float4-group index of the window

    const int tid  = threadIdx.x;
    const int b    = blockIdx.x / NTILES;
    const int tile = blockIdx.x % NTILES;
    const int row0 = tile * TILE;
    const float* xb = x + (size_t)b * T * C;

    // ---- stage x halo rows into LDS (zero-padded at batch edges) ----
    for (int s = tid; s < HR * (C / 4); s += NT) {
        const int lr = s >> 4;
        const int c4 = (s & 15) << 2;
        const int gr = row0 + lr - HALO;
        float4 v = make_float4(0.f, 0.f, 0.f, 0.f);
        if (gr >= 0 && gr < T) v = *(const float4*)(xb + (size_t)gr * C + c4);
        *(float4*)&sX[lr][c4] = v;
    }

    const int h = tid & 63;      // head-dim column this lane owns
    const int w = tid >> 6;      // wave id 0..3

    // W row for this lane in registers (16 KB per matrix, L2-resident across 512 blocks)
    float4 wr[16];
#pragma unroll
    for (int c4 = 0; c4 < 16; ++c4) wr[c4] = *(const float4*)(Wq + h * C + c4 * 4);

    __syncthreads();

    // ---- Q = X[tile] @ Wq^T : wave w computes rows w*8..w*8+7; sX row broadcast ----
#pragma unroll
    for (int ii = 0; ii < 8; ++ii) {
        const int i = w * 8 + ii;
        float acc = 0.f;
#pragma unroll
        for (int c4 = 0; c4 < 16; ++c4) {
            const float4 xv = *(const float4*)&sX[i + HALO][c4 * 4];
            acc = fmaf(xv.x, wr[c4].x, acc);
            acc = fmaf(xv.y, wr[c4].y, acc);
            acc = fmaf(xv.z, wr[c4].z, acc);
            acc = fmaf(xv.w, wr[c4].w, acc);
        }
        sQ[i][h] = acc;
    }

    // ---- K = X[halo] @ Wk^T : wave w computes rows w*9..w*9+8 ----
#pragma unroll
    for (int c4 = 0; c4 < 16; ++c4) wr[c4] = *(const float4*)(Wk + h * C + c4 * 4);
#pragma unroll
    for (int ii = 0; ii < 9; ++ii) {
        const int l = w * 9 + ii;
        float acc = 0.f;
#pragma unroll
        for (int c4 = 0; c4 < 16; ++c4) {
            const float4 xv = *(const float4*)&sX[l][c4 * 4];
            acc = fmaf(xv.x, wr[c4].x, acc);
            acc = fmaf(xv.y, wr[c4].y, acc);
            acc = fmaf(xv.z, wr[c4].z, acc);
            acc = fmaf(xv.w, wr[c4].w, acc);
        }
        sK[l][h] = acc;
    }

    // ---- V = X[halo] @ Wv^T ----
#pragma unroll
    for (int c4 = 0; c4 < 16; ++c4) wr[c4] = *(const float4*)(Wv + h * C + c4 * 4);
#pragma unroll
    for (int ii = 0; ii < 9; ++ii) {
        const int l = w * 9 + ii;
        float acc = 0.f;
#pragma unroll
        for (int c4 = 0; c4 < 16; ++c4) {
            const float4 xv = *(const float4*)&sX[l][c4 * 4];
            acc = fmaf(xv.x, wr[c4].x, acc);
            acc = fmaf(xv.y, wr[c4].y, acc);
            acc = fmaf(xv.z, wr[c4].z, acc);
            acc = fmaf(xv.w, wr[c4].w, acc);
        }
        sV[l][h] = acc;
    }

    __syncthreads();

    // ---- scores: 32 rows x 5 offsets on 160 threads ----
    if (tid < TILE * 5) {
        const int i  = tid / 5;
        const int dj = tid % 5;
        const int jg = row0 + i - HALO + dj;
        float sc = -__builtin_inff();
        if (jg >= 0 && jg < T) {
            float acc = 0.f;
#pragma unroll
            for (int c4 = 0; c4 < C; c4 += 4) {
                const float4 q = *(const float4*)&sQ[i][c4];
                const float4 k = *(const float4*)&sK[i + dj][c4];
                acc = fmaf(q.x, k.x, acc);
                acc = fmaf(q.y, k.y, acc);
                acc = fmaf(q.z, k.z, acc);
                acc = fmaf(q.w, k.w, acc);
            }
            // scale = C^-0.5 = 0.125 ; +1 bias inside band for j > i (dj > 2), per triu(ones,1)
            sc = acc * 0.125f + (dj > 2 ? 1.0f : 0.0f);
        }
        sS[i][dj] = sc;
    }
    __syncthreads();

    // ---- softmax per row; build aligned 8-float band window + group index ----
    if (tid < TILE) {
        const int i  = tid;
        const int ig = row0 + i;
        float sc[5];
        float m = -__builtin_inff();
#pragma unroll
        for (int d = 0; d < 5; ++d) { sc[d] = sS[i][d]; m = fmaxf(m, sc[d]); }
        float p[5];
        float sum = 0.f;
#pragma unroll
        for (int d = 0; d < 5; ++d) { p[d] = expf(sc[d] - m); sum += p[d]; }
        const float inv = 1.f / sum;

        const int j0   = ig - HALO;
        const int G0   = (j0 > 0 ? j0 : 0) >> 2;     // first touched float4 group
        const int base = G0 << 2;
        float bw[8];
#pragma unroll
        for (int q = 0; q < 8; ++q) bw[q] = 0.f;
#pragma unroll
        for (int d = 0; d < 5; ++d) {
            const float pv = p[d] * inv;             // exp(-inf)=0 -> prob 0 for invalid j
            sS[i][d] = pv;
            const int off = j0 + d - base;
            if (off >= 0 && off < 8) bw[off] = pv;   // j>=T slots carry prob 0, harmless
        }
        sBG[i] = G0;
        f32x4 v0, v1;
        v0.x = bw[0]; v0.y = bw[1]; v0.z = bw[2]; v0.w = bw[3];
        v1.x = bw[4]; v1.y = bw[5]; v1.z = bw[6]; v1.w = bw[7];
        sBV[i][0] = v0;
        sBV[i][1] = v1;
    }
    __syncthreads();

    // ================= no barriers below: pure streaming store phase =================

    // ---- op = P @ V : 512 float4 outputs, coalesced, nontemporal ----
    for (int s = tid; s < TILE * (H / 4); s += NT) {
        const int r  = s >> 4;
        const int hq = (s & 15) << 2;
        f32x4 acc = (f32x4)0.f;
#pragma unroll
        for (int d = 0; d < 5; ++d) {
            const float pv = sS[r][d];
            const float4 vv = *(const float4*)&sV[r + d][hq];
            acc.x = fmaf(pv, vv.x, acc.x);
            acc.y = fmaf(pv, vv.y, acc.y);
            acc.z = fmaf(pv, vv.z, acc.z);
            acc.w = fmaf(pv, vv.w, acc.w);
        }
        store_nt((f32x4*)(out + ((size_t)b * T + row0 + r) * H + hq), acc);
    }

    // ---- attn rows: each float4 written exactly once (zero or band window), nontemporal ----
    const size_t attnBase = (size_t)B * T * H;
    f32x4* dst = (f32x4*)(out + attnBase + ((size_t)b * T + row0) * T);
    const f32x4 z = (f32x4)0.f;

    // software-pipeline the per-row meta reads so lgkm latency never gates store issue
    int   G0n = sBG[0];
    f32x4 V0n = sBV[0][0];
    f32x4 V1n = sBV[0][1];
    for (int rr = 0; rr < TILE; ++rr) {
        const int   G0 = G0n;
        const f32x4 V0 = V0n;
        const f32x4 V1 = V1n;
        if (rr + 1 < TILE) {
            G0n = sBG[rr + 1];
            V0n = sBV[rr + 1][0];
            V1n = sBV[rr + 1][1];
        }
        f32x4* drow = dst + rr * (T / 4);
#pragma unroll
        for (int kk = 0; kk < 4; ++kk) {
            const int g = kk * NT + tid;             // wave-contiguous 1 KiB per store instr
            f32x4 v = z;
            v = (g == G0)     ? V0 : v;
            v = (g == G0 + 1) ? V1 : v;              // G0+1==1024 at top edge: never matches, fine
            store_nt(&drow[g], v);
        }
    }
}

extern "C" void kernel_launch(void* const* d_in, const int* in_sizes, int n_in,
                              void* d_out, int out_size, void* d_ws, size_t ws_size,
                              hipStream_t stream) {
    (void)in_sizes; (void)n_in; (void)d_ws; (void)ws_size; (void)out_size;
    const float* x  = (const float*)d_in[0];
    const float* Wq = (const float*)d_in[1];
    const float* Wk = (const float*)d_in[2];
    const float* Wv = (const float*)d_in[3];
    float* out = (float*)d_out;
    sparse_attn_fused<<<dim3(B * NTILES), dim3(NT), 0, stream>>>(x, Wq, Wk, Wv, out);
}

// Round 4
// 400.602 us; speedup vs baseline: 1.1207x; 1.0845x over previous
//
#include <hip/hip_runtime.h>

constexpr int B      = 4;
constexpr int T      = 4096;
constexpr int C      = 64;                 // input dim
constexpr int H      = 64;                 // head dim
constexpr int TILE   = 32;                 // query rows per block
constexpr int HALO   = 2;                  // window radius
constexpr int HR     = TILE + 2 * HALO;    // 36 halo rows
constexpr int LS     = 68;                 // LDS row stride (floats): float4-aligned, rotates banks by 4/row
constexpr int NT     = 256;
constexpr int NTILES = T / TILE;           // 128

typedef float f32x4 __attribute__((ext_vector_type(4)));

// Attn zeros are written by hipMemsetAsync (rocclr fillBuffer: 6.1 TB/s, zero
// RMW fetch — measured r1/r3). This kernel writes ONLY op + the <=2 aligned
// float4 band groups per attn row. In-kernel bulk zero-fill is ~2.5x
// traffic-amplified (r2/r3: FETCH=attn/2, WRITE=2x) — do not bring it back.
__global__ __launch_bounds__(NT, 2)
void sparse_attn_fused(const float* __restrict__ x,
                       const float* __restrict__ Wq,
                       const float* __restrict__ Wk,
                       const float* __restrict__ Wv,
                       float* __restrict__ out)
{
    __shared__ float sX[HR][LS];       // x halo rows
    __shared__ float sQ[TILE][LS];
    __shared__ float sK[HR][LS];
    __shared__ float sV[HR][LS];
    __shared__ float sS[TILE][8];      // scores, then probs (5 used per row)

    const int tid  = threadIdx.x;
    const int b    = blockIdx.x / NTILES;
    const int tile = blockIdx.x % NTILES;
    const int row0 = tile * TILE;
    const float* xb = x + (size_t)b * T * C;

    // ---- stage x halo rows into LDS (zero-padded at batch edges) ----
    for (int s = tid; s < HR * (C / 4); s += NT) {
        const int lr = s >> 4;
        const int c4 = (s & 15) << 2;
        const int gr = row0 + lr - HALO;
        float4 v = make_float4(0.f, 0.f, 0.f, 0.f);
        if (gr >= 0 && gr < T) v = *(const float4*)(xb + (size_t)gr * C + c4);
        *(float4*)&sX[lr][c4] = v;
    }

    const int h = tid & 63;      // head-dim column this lane owns
    const int w = tid >> 6;      // wave id 0..3

    // W row for this lane in registers (16 KB per matrix, L2-resident across 512 blocks)
    float4 wr[16];
#pragma unroll
    for (int c4 = 0; c4 < 16; ++c4) wr[c4] = *(const float4*)(Wq + h * C + c4 * 4);

    __syncthreads();

    // ---- Q = X[tile] @ Wq^T : wave w computes rows w*8..w*8+7; sX row broadcast ----
#pragma unroll
    for (int ii = 0; ii < 8; ++ii) {
        const int i = w * 8 + ii;
        float acc = 0.f;
#pragma unroll
        for (int c4 = 0; c4 < 16; ++c4) {
            const float4 xv = *(const float4*)&sX[i + HALO][c4 * 4];
            acc = fmaf(xv.x, wr[c4].x, acc);
            acc = fmaf(xv.y, wr[c4].y, acc);
            acc = fmaf(xv.z, wr[c4].z, acc);
            acc = fmaf(xv.w, wr[c4].w, acc);
        }
        sQ[i][h] = acc;
    }

    // ---- K = X[halo] @ Wk^T : wave w computes rows w*9..w*9+8 ----
#pragma unroll
    for (int c4 = 0; c4 < 16; ++c4) wr[c4] = *(const float4*)(Wk + h * C + c4 * 4);
#pragma unroll
    for (int ii = 0; ii < 9; ++ii) {
        const int l = w * 9 + ii;
        float acc = 0.f;
#pragma unroll
        for (int c4 = 0; c4 < 16; ++c4) {
            const float4 xv = *(const float4*)&sX[l][c4 * 4];
            acc = fmaf(xv.x, wr[c4].x, acc);
            acc = fmaf(xv.y, wr[c4].y, acc);
            acc = fmaf(xv.z, wr[c4].z, acc);
            acc = fmaf(xv.w, wr[c4].w, acc);
        }
        sK[l][h] = acc;
    }

    // ---- V = X[halo] @ Wv^T ----
#pragma unroll
    for (int c4 = 0; c4 < 16; ++c4) wr[c4] = *(const float4*)(Wv + h * C + c4 * 4);
#pragma unroll
    for (int ii = 0; ii < 9; ++ii) {
        const int l = w * 9 + ii;
        float acc = 0.f;
#pragma unroll
        for (int c4 = 0; c4 < 16; ++c4) {
            const float4 xv = *(const float4*)&sX[l][c4 * 4];
            acc = fmaf(xv.x, wr[c4].x, acc);
            acc = fmaf(xv.y, wr[c4].y, acc);
            acc = fmaf(xv.z, wr[c4].z, acc);
            acc = fmaf(xv.w, wr[c4].w, acc);
        }
        sV[l][h] = acc;
    }

    __syncthreads();

    // ---- scores: 32 rows x 5 offsets on 160 threads ----
    if (tid < TILE * 5) {
        const int i  = tid / 5;
        const int dj = tid % 5;
        const int jg = row0 + i - HALO + dj;
        float sc = -__builtin_inff();
        if (jg >= 0 && jg < T) {
            float acc = 0.f;
#pragma unroll
            for (int c4 = 0; c4 < C; c4 += 4) {
                const float4 q = *(const float4*)&sQ[i][c4];
                const float4 k = *(const float4*)&sK[i + dj][c4];
                acc = fmaf(q.x, k.x, acc);
                acc = fmaf(q.y, k.y, acc);
                acc = fmaf(q.z, k.z, acc);
                acc = fmaf(q.w, k.w, acc);
            }
            // scale = C^-0.5 = 0.125 ; +1 bias inside band for j > i (dj > 2), per triu(ones,1)
            sc = acc * 0.125f + (dj > 2 ? 1.0f : 0.0f);
        }
        sS[i][dj] = sc;
    }
    __syncthreads();

    // ---- softmax per row; write the <=2 aligned float4 band groups directly ----
    const size_t attnBase = (size_t)B * T * H;
    if (tid < TILE) {
        const int i  = tid;
        const int ig = row0 + i;
        float sc[5];
        float m = -__builtin_inff();
#pragma unroll
        for (int d = 0; d < 5; ++d) { sc[d] = sS[i][d]; m = fmaxf(m, sc[d]); }
        float p[5];
        float sum = 0.f;
#pragma unroll
        for (int d = 0; d < 5; ++d) { p[d] = expf(sc[d] - m); sum += p[d]; }
        const float inv = 1.f / sum;

        const int j0   = ig - HALO;
        const int G0   = (j0 > 0 ? j0 : 0) >> 2;     // first touched float4 group
        const int base = G0 << 2;
        float bw[8];
#pragma unroll
        for (int q = 0; q < 8; ++q) bw[q] = 0.f;
#pragma unroll
        for (int d = 0; d < 5; ++d) {
            const float pv = p[d] * inv;             // exp(-inf)=0 -> prob 0 for invalid j
            sS[i][d] = pv;
            const int off = j0 + d - base;
            if (off >= 0 && off < 8) bw[off] = pv;   // j>=T slots carry prob 0, harmless
        }
        f32x4* drow = (f32x4*)(out + attnBase + ((size_t)b * T + ig) * T);
        f32x4 v0; v0.x = bw[0]; v0.y = bw[1]; v0.z = bw[2]; v0.w = bw[3];
        drow[G0] = v0;
        if (G0 + 1 < T / 4) {                        // top edge: window tail is all zeros
            f32x4 v1; v1.x = bw[4]; v1.y = bw[5]; v1.z = bw[6]; v1.w = bw[7];
            drow[G0 + 1] = v1;                       // (memset already zeroed; skip avoids
        }                                            //  racing the next batch's row 0)
    }
    __syncthreads();

    // ---- op = P @ V : 512 float4 outputs, coalesced ----
    for (int s = tid; s < TILE * (H / 4); s += NT) {
        const int r  = s >> 4;
        const int hq = (s & 15) << 2;
        float4 acc = make_float4(0.f, 0.f, 0.f, 0.f);
#pragma unroll
        for (int d = 0; d < 5; ++d) {
            const float pv = sS[r][d];
            const float4 vv = *(const float4*)&sV[r + d][hq];
            acc.x = fmaf(pv, vv.x, acc.x);
            acc.y = fmaf(pv, vv.y, acc.y);
            acc.z = fmaf(pv, vv.z, acc.z);
            acc.w = fmaf(pv, vv.w, acc.w);
        }
        *(float4*)(out + ((size_t)b * T + row0 + r) * H + hq) = acc;
    }
}

extern "C" void kernel_launch(void* const* d_in, const int* in_sizes, int n_in,
                              void* d_out, int out_size, void* d_ws, size_t ws_size,
                              hipStream_t stream) {
    (void)in_sizes; (void)n_in; (void)d_ws; (void)ws_size; (void)out_size;
    const float* x  = (const float*)d_in[0];
    const float* Wq = (const float*)d_in[1];
    const float* Wk = (const float*)d_in[2];
    const float* Wv = (const float*)d_in[3];
    float* out = (float*)d_out;

    // Zero the dense attn region via the runtime fill kernel (pure streaming
    // writes, 6.1 TB/s, zero RMW fetch — measured). Stream order makes the
    // fill complete before the band stores in sparse_attn_fused.
    float* attn = out + (size_t)B * T * H;
    hipMemsetAsync((void*)attn, 0, (size_t)B * T * T * sizeof(float), stream);

    sparse_attn_fused<<<dim3(B * NTILES), dim3(NT), 0, stream>>>(x, Wq, Wk, Wv, out);
}